// Round 9
// baseline (906.573 us; speedup 1.0000x reference)
//
#include <hip/hip_runtime.h>
#include <math.h>

// Problem constants
#define Bq   256
#define Hd   2048
#define Ed   256
#define Ni   200000
#define Tt   4
#define NBITS 8
#define Kk   100
#define Mm   128            // rerank margin: top-128 by approx key superset of true top-100
#define CAPL 16384          // per-query compact candidate list capacity
#define CAPB 3072           // per-block LDS match buffer (slice expects ~390)
#define CAP2 4096           // select LDS collect capacity
#define NBINS 8192
#define NSLICE 8
#define ISLICE (Ni / NSLICE)   // 25000
#define IPB 256              // icode items per block
#define CE  64               // icode e-chunk
#define QPB 8                // qproj queries per block
#define QT  (Bq / QPB)       // 32 q-tiles
#define KC  16               // k-chunks
#define KCH (Hd / KC)        // 128

// ws layout (bytes) — total ~145.8 MB
#define OFF_QV64  0ull            // 256*256*8   = 524288
#define OFF_QC    524288ull       // 256*4       = 1024
#define OFF_IC    525312ull       // 200000*4    = 800000
#define OFF_CNT   1325312ull      // 256*4       = 1024
#define OFF_CAND  1326336ull      // 256*128*4   = 131072
#define OFF_IBF   1457408ull      // 200000*256*2 = 102400000
#define OFF_LIST  103857408ull    // 256*16384*8  = 33554432
#define OFF_PART  137411840ull    // 16*256*256*8 = 8388608

__device__ __forceinline__ unsigned short f2bf(float x) {
  unsigned u = __float_as_uint(x);
  return (unsigned short)((u + 0x7FFFu + ((u >> 16) & 1u)) >> 16);
}
__device__ __forceinline__ float bf2f(unsigned short h) {
  return __uint_as_float((unsigned)h << 16);
}
__device__ __forceinline__ bool anybyte_eq(unsigned a, unsigned b) {
  unsigned x = a ^ b;
  return ((x - 0x01010101u) & ~x & 0x80808080u) != 0u;
}
__device__ __forceinline__ unsigned fkey(float s) {
  unsigned u = __float_as_uint(s);
  return (u & 0x80000000u) ? ~u : (u | 0x80000000u);
}

// histogram beta-find helper (shared across select/fallback)
__device__ __forceinline__ int find_beta(unsigned* hist, unsigned* partial_,
                                         int* sbeta, int tid, int target) {
  unsigned s = 0;
#pragma unroll 8
  for (int j = 0; j < 32; ++j) s += hist[tid * 32 + j];
  partial_[tid] = s;
  __syncthreads();
  if (tid == 0) {
    unsigned cum = 0;
    int c;
    for (c = 255; c > 0; --c) {
      if (cum + partial_[c] >= (unsigned)target) break;
      cum += partial_[c];
    }
    int b;
    for (b = c * 32 + 31; b > c * 32; --b) {
      if (cum + hist[b] >= (unsigned)target) break;
      cum += hist[b];
    }
    *sbeta = b;
  }
  __syncthreads();
  return *sbeta;
}

// ---------------------------------------------------------------------------
// Kernel A1: split-K f64 projection GEMM. grid (32 qtiles, 16 kchunks) x 256.
// ---------------------------------------------------------------------------
__global__ void __launch_bounds__(256) qproj_gemm(
    const float* __restrict__ hidden,
    const float* __restrict__ Wq,
    double* __restrict__ partial) {
  __shared__ float hs_t[KCH][QPB];   // [h][qq], 4 KB
  const int e = threadIdx.x;
  const int qbase = blockIdx.x * QPB;
  const int kc = blockIdx.y;

  for (int j = e; j < QPB * KCH; j += 256) {
    int qq = j >> 7, h = j & (KCH - 1);
    hs_t[h][qq] = hidden[(size_t)(qbase + qq) * Hd + kc * KCH + h];
  }
  __syncthreads();

  double acc[QPB];
#pragma unroll
  for (int qq = 0; qq < QPB; ++qq) acc[qq] = 0.0;

  for (int h = 0; h < KCH; ++h) {
    double w = (double)Wq[(size_t)(kc * KCH + h) * Ed + e];
    float4 ha = *reinterpret_cast<const float4*>(&hs_t[h][0]);
    float4 hb = *reinterpret_cast<const float4*>(&hs_t[h][4]);
    acc[0] = fma((double)ha.x, w, acc[0]);
    acc[1] = fma((double)ha.y, w, acc[1]);
    acc[2] = fma((double)ha.z, w, acc[2]);
    acc[3] = fma((double)ha.w, w, acc[3]);
    acc[4] = fma((double)hb.x, w, acc[4]);
    acc[5] = fma((double)hb.y, w, acc[5]);
    acc[6] = fma((double)hb.z, w, acc[6]);
    acc[7] = fma((double)hb.w, w, acc[7]);
  }

#pragma unroll
  for (int qq = 0; qq < QPB; ++qq)
    partial[((size_t)kc * Bq + qbase + qq) * Ed + e] = acc[qq];
}

// ---------------------------------------------------------------------------
// Kernel A2: finalize — sum 16 partials + LayerNorm + tanh + fused qcode.
// ---------------------------------------------------------------------------
__global__ void qproj_fin(const double* __restrict__ partial,
                          const float* __restrict__ bq,
                          const float* __restrict__ gamma,
                          const float* __restrict__ beta,
                          const float* __restrict__ proj,
                          float* __restrict__ out_qv,
                          double* __restrict__ qv64,
                          unsigned* __restrict__ qcp,
                          unsigned* __restrict__ cnt) {
  const int q = blockIdx.x, e = threadIdx.x;
  __shared__ double red[256];
  __shared__ double qd[256];
  __shared__ double s_mu, s_rs;

  if (e == 0) cnt[q] = 0u;

  double acc = 0.0;
#pragma unroll
  for (int kc = 0; kc < KC; ++kc)
    acc += partial[((size_t)kc * Bq + q) * Ed + e];
  acc += (double)bq[e];

  red[e] = acc;
  __syncthreads();
  for (int s = 128; s > 0; s >>= 1) {
    if (e < s) red[e] += red[e + s];
    __syncthreads();
  }
  if (e == 0) s_mu = red[0] / 256.0;
  __syncthreads();
  double d = acc - s_mu;
  red[e] = d * d;
  __syncthreads();
  for (int s = 128; s > 0; s >>= 1) {
    if (e < s) red[e] += red[e + s];
    __syncthreads();
  }
  if (e == 0) s_rs = 1.0 / sqrt(red[0] / 256.0 + 1e-5);
  __syncthreads();

  double y = (acc - s_mu) * s_rs * (double)gamma[e] + (double)beta[e];
  double t = tanh(y);
  out_qv[(size_t)q * Ed + e] = (float)t;
  qv64[(size_t)q * Ed + e] = t;
  qd[e] = t;
  __syncthreads();

  double dot = 0.0;
  if (e < 32) {
    const int tt = e >> 3, b = e & 7;
    const float* pp = proj + (size_t)tt * Ed * NBITS + b;
#pragma unroll 4
    for (int ee = 0; ee < Ed; ++ee)
      dot = fma(qd[ee], (double)pp[(size_t)ee * NBITS], dot);
  }
  unsigned long long mask = __ballot(e < 32 && dot > 0.0);
  if (e == 0) qcp[q] = (unsigned)mask;
}

// ---------------------------------------------------------------------------
// Kernel I (v7): single-pass icode via bf16 LDS tile. grid 782 x 256.
// Per CE=64 chunk: stage 256 rows coalesced (float4), convert once to bf16,
// write ushort4 to LDS tile [256][72] (36.8 KB -> 4 blocks/CU) AND to ibf
// (128B full lines, R7-proven WRITE=101MB). Compute thread=item from LDS
// (8 x b128/chunk, bank-uniform), f32 FMA on bf16 inputs + running ||item||^2.
// Deterministic borderline bound: |err| <= ||item||*(2^-9 + accum) (proj
// columns unit-norm) -> flag |acc| < 2.1e-3*||item||, per-bit f64 recompute
// from ORIGINAL f32 item (8x-proven exact path).
// ---------------------------------------------------------------------------
#define TSS 72   // LDS row stride in shorts (144 B)
__global__ void __launch_bounds__(256) icode_kernel(
    const float* __restrict__ item,
    const float* __restrict__ proj,
    unsigned* __restrict__ icodes,
    unsigned short* __restrict__ ibf) {
  __shared__ unsigned short ts[IPB * TSS];   // 36864 B
  const int tid = threadIdx.x;
  const int base = blockIdx.x * IPB;
  const int gi = base + tid;
  const float4* item4 = reinterpret_cast<const float4*>(item);
  const float4* pj = reinterpret_cast<const float4*>(proj);  // (t,e): t*512+e*2

  float acc[32];
#pragma unroll
  for (int b = 0; b < 32; ++b) acc[b] = 0.0f;
  float nrm = 0.0f;

  const int srow = tid >> 4, sc4 = tid & 15;   // 16 lanes per row

  for (int c = 0; c < Ed / CE; ++c) {          // 4 chunks
    __syncthreads();
    // stage: 16 reps x (16 rows x 16 lanes x 16B f32) -> bf16 LDS + ibf
#pragma unroll 4
    for (int r = 0; r < 16; ++r) {
      const int row = srow + 16 * r;
      const int g = base + row;
      float4 v = make_float4(0.f, 0.f, 0.f, 0.f);
      if (g < Ni) v = item4[(size_t)g * 64 + c * 16 + sc4];
      ushort4 hv;
      hv.x = f2bf(v.x); hv.y = f2bf(v.y); hv.z = f2bf(v.z); hv.w = f2bf(v.w);
      *reinterpret_cast<ushort4*>(&ts[row * TSS + sc4 * 4]) = hv;
      if (g < Ni)
        *reinterpret_cast<ushort4*>(&ibf[(size_t)g * Ed + c * CE + sc4 * 4]) = hv;
    }
    __syncthreads();

    // compute: thread = item row tid; 8 x b128 (8 bf16 each)
#pragma unroll
    for (int e8 = 0; e8 < CE / 8; ++e8) {
      const uint4 hw = *reinterpret_cast<const uint4*>(&ts[tid * TSS + e8 * 8]);
      const unsigned pk[4] = {hw.x, hw.y, hw.z, hw.w};
#pragma unroll
      for (int p2 = 0; p2 < 4; ++p2) {
        const float f0 = __uint_as_float(pk[p2] << 16);
        const float f1 = __uint_as_float(pk[p2] & 0xFFFF0000u);
        const float fv[2] = {f0, f1};
#pragma unroll
        for (int k = 0; k < 2; ++k) {
          const float av = fv[k];
          const int e = c * CE + e8 * 8 + p2 * 2 + k;
          nrm = fmaf(av, av, nrm);
#pragma unroll
          for (int t = 0; t < 4; ++t) {
            const float4 pa = pj[t * 512 + e * 2];
            const float4 pb = pj[t * 512 + e * 2 + 1];
            const int o = t * 8;
            acc[o + 0] = fmaf(av, pa.x, acc[o + 0]);
            acc[o + 1] = fmaf(av, pa.y, acc[o + 1]);
            acc[o + 2] = fmaf(av, pa.z, acc[o + 2]);
            acc[o + 3] = fmaf(av, pa.w, acc[o + 3]);
            acc[o + 4] = fmaf(av, pb.x, acc[o + 4]);
            acc[o + 5] = fmaf(av, pb.y, acc[o + 5]);
            acc[o + 6] = fmaf(av, pb.z, acc[o + 6]);
            acc[o + 7] = fmaf(av, pb.w, acc[o + 7]);
          }
        }
      }
    }
  }

  if (gi >= Ni) return;

  const float thr = 2.1e-3f * sqrtf(nrm);
  unsigned code = 0, bl = 0;
#pragma unroll
  for (int b = 0; b < 32; ++b) {
    code |= (acc[b] > 0.0f ? 1u : 0u) << b;
    bl |= (fabsf(acc[b]) < thr ? 1u : 0u) << b;
  }

  if (bl) {   // borderline exact f64 path from original f32 item (~5% items)
    const float* er = item + (size_t)gi * Ed;
    while (bl) {
      const int b = __builtin_ctz(bl);
      bl &= bl - 1;
      const int t = b >> 3, bit = b & 7;
      const float* pp = proj + (size_t)t * (Ed * NBITS) + bit;
      double a = 0.0;
      for (int e2 = 0; e2 < Ed; ++e2)
        a = fma((double)er[e2], (double)pp[(size_t)e2 * NBITS], a);
      if (a > 0.0) code |= 1u << b; else code &= ~(1u << b);
    }
  }
  icodes[gi] = code;
}

// ---------------------------------------------------------------------------
// Kernel F: fused match + candidate scoring. grid (256 q, 8 slices) x 256.
// ---------------------------------------------------------------------------
__global__ void __launch_bounds__(256) score_kernel(
    const float* __restrict__ qvf,
    const unsigned short* __restrict__ ibf,
    const unsigned* __restrict__ icodes,
    const unsigned* __restrict__ qcp,
    unsigned* __restrict__ cnt,
    unsigned long long* __restrict__ list) {
  __shared__ unsigned long long buf[CAPB];   // 24 KB
  __shared__ int lcnt;
  __shared__ unsigned sbase;

  const int tid = threadIdx.x;
  const int q = blockIdx.x;
  const int sl = blockIdx.y;
  const int l = tid & 63, wid = tid >> 6;

  if (tid == 0) lcnt = 0;
  const unsigned qc = qcp[q];
  const float4 qv4 = *reinterpret_cast<const float4*>(&qvf[(size_t)q * Ed + l * 4]);
  __syncthreads();

  const int i0 = sl * ISLICE, i1 = i0 + ISLICE;
  for (int bse = i0 + wid * 64; bse < i1; bse += 256) {
    const int i = bse + l;
    bool m = (i < i1) && anybyte_eq(qc, icodes[i]);
    unsigned long long mask = __ballot(m);
    while (mask) {
      const int b = __builtin_ctzll(mask);
      mask &= mask - 1;
      const int ii = bse + b;
      ushort4 hv = *reinterpret_cast<const ushort4*>(&ibf[(size_t)ii * Ed + l * 4]);
      float p = fmaf(bf2f(hv.x), qv4.x,
                fmaf(bf2f(hv.y), qv4.y,
                fmaf(bf2f(hv.z), qv4.z, bf2f(hv.w) * qv4.w)));
#pragma unroll
      for (int off = 1; off < 64; off <<= 1) p += __shfl_xor(p, off);
      if (l == 0) {
        int pos = atomicAdd(&lcnt, 1);
        if (pos < CAPB)
          buf[pos] = ((unsigned long long)fkey(p) << 32) |
                     (unsigned)(~(unsigned)ii);
      }
    }
  }
  __syncthreads();

  const int nl = lcnt;
  if (nl > CAPB) {           // overflow: force brute-force fallback for q
    if (tid == 0) atomicAdd(&cnt[q], (unsigned)(CAPL + 1));
    return;
  }
  if (tid == 0) sbase = atomicAdd(&cnt[q], (unsigned)nl);
  __syncthreads();
  const unsigned bp = sbase;
  for (int j = tid; j < nl; j += 256) {
    unsigned p = bp + (unsigned)j;
    if (p < CAPL) list[(size_t)q * CAPL + p] = buf[j];
  }
}

// ---------------------------------------------------------------------------
// Kernel FB: brute-force fallback for queries with cnt<Mm or overflow.
// ---------------------------------------------------------------------------
__global__ void fallback_kernel(const double* __restrict__ qv64,
                                const float* __restrict__ item,
                                const unsigned* __restrict__ qcp,
                                const unsigned* __restrict__ icodes,
                                unsigned* __restrict__ cnt,
                                unsigned long long* __restrict__ list) {
  const int q = blockIdx.x, tid = threadIdx.x;
  unsigned c = cnt[q];
  if (c >= (unsigned)Mm && c <= (unsigned)CAPL) return;

  __shared__ unsigned hist[NBINS];
  __shared__ float qf[256];
  __shared__ unsigned partial_[256];
  __shared__ int sbeta, scnt;

  qf[tid] = (float)qv64[(size_t)q * Ed + tid];
  for (int j = tid; j < NBINS; j += 256) hist[j] = 0u;
  if (tid == 0) scnt = 0;
  __syncthreads();

  const unsigned qc = qcp[q];
  for (int i = tid; i < Ni; i += 256) {
    float s = 0.0f;
    const float* er = item + (size_t)i * Ed;
    for (int e = 0; e < Ed; ++e) s = fmaf(qf[e], er[e], s);
    if (!anybyte_eq(qc, icodes[i])) s -= 1.0e6f;
    atomicAdd(&hist[fkey(s) >> 19], 1u);
  }
  __syncthreads();

  int beta = find_beta(hist, partial_, &sbeta, tid, Mm);
  __syncthreads();

  for (int i = tid; i < Ni; i += 256) {
    float s = 0.0f;
    const float* er = item + (size_t)i * Ed;
    for (int e = 0; e < Ed; ++e) s = fmaf(qf[e], er[e], s);
    if (!anybyte_eq(qc, icodes[i])) s -= 1.0e6f;
    unsigned k = fkey(s);
    if ((int)(k >> 19) >= beta) {
      int pos = atomicAdd(&scnt, 1);
      if (pos < CAPL)
        list[(size_t)q * CAPL + pos] =
            ((unsigned long long)k << 32) | (unsigned)(~(unsigned)i);
    }
  }
  __syncthreads();
  if (tid == 0) cnt[q] = (unsigned)(scnt < CAPL ? scnt : CAPL);
}

// ---------------------------------------------------------------------------
// Kernel D: top-128 select from compact list (hist threshold + bitonic).
// ---------------------------------------------------------------------------
__global__ void select_kernel(const unsigned long long* __restrict__ list,
                              const unsigned* __restrict__ cnt,
                              unsigned* __restrict__ cand) {
  __shared__ unsigned long long buf[CAP2];   // 32 KB (aliased with hist)
  __shared__ unsigned partial_[256];
  __shared__ int sbeta, scnt;
  unsigned* hist = reinterpret_cast<unsigned*>(buf);

  const int q = blockIdx.x, tid = threadIdx.x;
  const unsigned long long* src = list + (size_t)q * CAPL;
  const int count = min((int)cnt[q], CAPL);

  for (int j = tid; j < NBINS; j += 256) hist[j] = 0u;
  if (tid == 0) scnt = 0;
  __syncthreads();

  for (int i = tid; i < count; i += 256)
    atomicAdd(&hist[(unsigned)(src[i] >> 32) >> 19], 1u);
  __syncthreads();

  int beta = find_beta(hist, partial_, &sbeta, tid, Mm);
  __syncthreads();   // hist dead; buf reuse begins

  for (int i = tid; i < count; i += 256) {
    unsigned long long v = src[i];
    if ((int)((unsigned)(v >> 32) >> 19) >= beta) {
      int pos = atomicAdd(&scnt, 1);
      if (pos < CAP2) buf[pos] = v;
    }
  }
  __syncthreads();

  int sc = min(scnt, CAP2);
  int n = Mm;
  while (n < sc) n <<= 1;
  for (int j = tid; j < n; j += 256)
    if (j >= sc) buf[j] = 0ull;
  __syncthreads();

  for (int k2 = 2; k2 <= n; k2 <<= 1) {
    for (int j = k2 >> 1; j > 0; j >>= 1) {
      for (int i = tid; i < n; i += 256) {
        int p = i ^ j;
        if (p > i) {
          bool up = ((i & k2) == 0);
          unsigned long long a = buf[i], b = buf[p];
          if ((a < b) == up) { buf[i] = b; buf[p] = a; }
        }
      }
      __syncthreads();
    }
  }

  if (tid < Mm)
    cand[q * Mm + tid] = ~(unsigned)(buf[tid] & 0xFFFFFFFFull);
}

// ---------------------------------------------------------------------------
// Kernel E: f64 re-rank of 128 candidates (wave-cooperative dots);
// sort (score desc, id asc); emit 100 ids (as f32) + gathered embeddings.
// ---------------------------------------------------------------------------
__global__ void rerank_kernel(const double* __restrict__ qv64,
                              const float* __restrict__ item,
                              const unsigned* __restrict__ qcp,
                              const unsigned* __restrict__ icodes,
                              const unsigned* __restrict__ cand,
                              float* __restrict__ out_ids,
                              float* __restrict__ out_emb) {
  const int q = blockIdx.x, tid = threadIdx.x;
  const int l = tid & 63, w = tid >> 6;
  __shared__ double qr[Ed];
  __shared__ double sc[Mm];
  __shared__ int sid[Mm];

  qr[tid] = qv64[(size_t)q * Ed + tid];
  if (tid < Mm) {
    int id = (int)cand[q * Mm + tid];
    if (id < 0 || id >= Ni) id = 0;
    sid[tid] = id;
  }
  __syncthreads();

  const unsigned qc = qcp[q];
  for (int cc = 0; cc < Mm / 4; ++cc) {
    const int ci = w * (Mm / 4) + cc;
    const int id = sid[ci];
    float4 ev = *reinterpret_cast<const float4*>(&item[(size_t)id * Ed + l * 4]);
    double p = fma((double)ev.x, qr[l * 4 + 0],
               fma((double)ev.y, qr[l * 4 + 1],
               fma((double)ev.z, qr[l * 4 + 2],
                   (double)ev.w * qr[l * 4 + 3])));
#pragma unroll
    for (int off = 32; off > 0; off >>= 1) p += __shfl_down(p, off);
    if (l == 0) {
      double s = p;
      if (!anybyte_eq(qc, icodes[id])) s -= 1.0e6;
      sc[ci] = s;
    }
  }
  __syncthreads();

  for (int k2 = 2; k2 <= Mm; k2 <<= 1) {
    for (int j = k2 >> 1; j > 0; j >>= 1) {
      for (int i = tid; i < Mm; i += 256) {
        int p = i ^ j;
        if (p > i) {
          bool up = ((i & k2) == 0);
          double sa = sc[i], sb = sc[p];
          int ia = sid[i], ib = sid[p];
          bool aAfterB = (sa < sb) || (sa == sb && ia > ib);
          if (aAfterB == up) {
            sc[i] = sb; sc[p] = sa;
            sid[i] = ib; sid[p] = ia;
          }
        }
      }
      __syncthreads();
    }
  }

  if (tid < Kk) out_ids[q * Kk + tid] = (float)sid[tid];
  for (int f = tid; f < Kk * 64; f += 256) {
    int r = f >> 6, c4 = f & 63;
    *reinterpret_cast<float4*>(&out_emb[((size_t)q * Kk + r) * Ed + c4 * 4]) =
        *reinterpret_cast<const float4*>(&item[(size_t)sid[r] * Ed + c4 * 4]);
  }
}

// ---------------------------------------------------------------------------
extern "C" void kernel_launch(void* const* d_in, const int* in_sizes, int n_in,
                              void* d_out, int out_size, void* d_ws, size_t ws_size,
                              hipStream_t stream) {
  const float* hidden = (const float*)d_in[0];
  const float* Wq     = (const float*)d_in[1];
  const float* bq     = (const float*)d_in[2];
  const float* gamma  = (const float*)d_in[3];
  const float* beta   = (const float*)d_in[4];
  const float* proj   = (const float*)d_in[5];
  const float* item   = (const float*)d_in[6];

  float* out = (float*)d_out;
  char* ws = (char*)d_ws;
  double*             qv64 = (double*)(ws + OFF_QV64);
  unsigned*           qcp  = (unsigned*)(ws + OFF_QC);
  unsigned*           ic   = (unsigned*)(ws + OFF_IC);
  unsigned*           cnt  = (unsigned*)(ws + OFF_CNT);
  unsigned*           cand = (unsigned*)(ws + OFF_CAND);
  unsigned short*     ibf  = (unsigned short*)(ws + OFF_IBF);
  unsigned long long* list = (unsigned long long*)(ws + OFF_LIST);
  double*             part = (double*)(ws + OFF_PART);

  qproj_gemm<<<dim3(QT, KC), dim3(256), 0, stream>>>(hidden, Wq, part);
  icode_kernel<<<dim3((Ni + IPB - 1) / IPB), dim3(256), 0, stream>>>(item, proj, ic, ibf);
  qproj_fin<<<dim3(Bq), dim3(256), 0, stream>>>(part, bq, gamma, beta, proj,
                                                out, qv64, qcp, cnt);
  score_kernel<<<dim3(Bq, NSLICE), dim3(256), 0, stream>>>(out, ibf, ic, qcp, cnt, list);
  fallback_kernel<<<dim3(Bq), dim3(256), 0, stream>>>(qv64, item, qcp, ic, cnt, list);
  select_kernel<<<dim3(Bq), dim3(256), 0, stream>>>(list, cnt, cand);
  rerank_kernel<<<dim3(Bq), dim3(256), 0, stream>>>(
      qv64, item, qcp, ic, cand,
      out + (size_t)Bq * Ed, out + (size_t)Bq * Ed + (size_t)Bq * Kk);
}

// Round 10
// 443.517 us; speedup vs baseline: 2.0441x; 2.0441x over previous
//
#include <hip/hip_runtime.h>
#include <math.h>

// Problem constants
#define Bq   256
#define Hd   2048
#define Ed   256
#define Ni   200000
#define Tt   4
#define NBITS 8
#define Kk   100
#define Mm   128            // rerank margin: top-128 by approx key superset of true top-100
#define CAPL 16384          // per-query compact candidate list capacity
#define CAPB 3072           // per-block LDS match buffer (slice expects ~390)
#define CAP2 4096           // select LDS collect capacity
#define NBINS 8192
#define NSLICE 8
#define ISLICE (Ni / NSLICE)   // 25000
#define IPB 64               // icode items per block (200000/64 = 3125 exact)
#define QPB 8                // qproj queries per block
#define QT  (Bq / QPB)       // 32 q-tiles
#define KC  16               // k-chunks
#define KCH (Hd / KC)        // 128

// ws layout (bytes) — total ~145.8 MB
#define OFF_QV64  0ull            // 256*256*8   = 524288
#define OFF_QC    524288ull       // 256*4       = 1024
#define OFF_IC    525312ull       // 200000*4    = 800000
#define OFF_CNT   1325312ull      // 256*4       = 1024
#define OFF_CAND  1326336ull      // 256*128*4   = 131072
#define OFF_IBF   1457408ull      // 200000*256*2 = 102400000
#define OFF_LIST  103857408ull    // 256*16384*8  = 33554432
#define OFF_PART  137411840ull    // 16*256*256*8 = 8388608

__device__ __forceinline__ unsigned short f2bf(float x) {
  unsigned u = __float_as_uint(x);
  return (unsigned short)((u + 0x7FFFu + ((u >> 16) & 1u)) >> 16);
}
__device__ __forceinline__ float bf2f(unsigned short h) {
  return __uint_as_float((unsigned)h << 16);
}
__device__ __forceinline__ bool anybyte_eq(unsigned a, unsigned b) {
  unsigned x = a ^ b;
  return ((x - 0x01010101u) & ~x & 0x80808080u) != 0u;
}
__device__ __forceinline__ unsigned fkey(float s) {
  unsigned u = __float_as_uint(s);
  return (u & 0x80000000u) ? ~u : (u | 0x80000000u);
}

// histogram beta-find helper (shared across select/fallback)
__device__ __forceinline__ int find_beta(unsigned* hist, unsigned* partial_,
                                         int* sbeta, int tid, int target) {
  unsigned s = 0;
#pragma unroll 8
  for (int j = 0; j < 32; ++j) s += hist[tid * 32 + j];
  partial_[tid] = s;
  __syncthreads();
  if (tid == 0) {
    unsigned cum = 0;
    int c;
    for (c = 255; c > 0; --c) {
      if (cum + partial_[c] >= (unsigned)target) break;
      cum += partial_[c];
    }
    int b;
    for (b = c * 32 + 31; b > c * 32; --b) {
      if (cum + hist[b] >= (unsigned)target) break;
      cum += hist[b];
    }
    *sbeta = b;
  }
  __syncthreads();
  return *sbeta;
}

// ---------------------------------------------------------------------------
// Kernel A1: split-K f64 projection GEMM. grid (32 qtiles, 16 kchunks) x 256.
// ---------------------------------------------------------------------------
__global__ void __launch_bounds__(256) qproj_gemm(
    const float* __restrict__ hidden,
    const float* __restrict__ Wq,
    double* __restrict__ partial) {
  __shared__ float hs_t[KCH][QPB];   // [h][qq], 4 KB
  const int e = threadIdx.x;
  const int qbase = blockIdx.x * QPB;
  const int kc = blockIdx.y;

  for (int j = e; j < QPB * KCH; j += 256) {
    int qq = j >> 7, h = j & (KCH - 1);
    hs_t[h][qq] = hidden[(size_t)(qbase + qq) * Hd + kc * KCH + h];
  }
  __syncthreads();

  double acc[QPB];
#pragma unroll
  for (int qq = 0; qq < QPB; ++qq) acc[qq] = 0.0;

  for (int h = 0; h < KCH; ++h) {
    double w = (double)Wq[(size_t)(kc * KCH + h) * Ed + e];
    float4 ha = *reinterpret_cast<const float4*>(&hs_t[h][0]);
    float4 hb = *reinterpret_cast<const float4*>(&hs_t[h][4]);
    acc[0] = fma((double)ha.x, w, acc[0]);
    acc[1] = fma((double)ha.y, w, acc[1]);
    acc[2] = fma((double)ha.z, w, acc[2]);
    acc[3] = fma((double)ha.w, w, acc[3]);
    acc[4] = fma((double)hb.x, w, acc[4]);
    acc[5] = fma((double)hb.y, w, acc[5]);
    acc[6] = fma((double)hb.z, w, acc[6]);
    acc[7] = fma((double)hb.w, w, acc[7]);
  }

#pragma unroll
  for (int qq = 0; qq < QPB; ++qq)
    partial[((size_t)kc * Bq + qbase + qq) * Ed + e] = acc[qq];
}

// ---------------------------------------------------------------------------
// Kernel A2: finalize — sum 16 partials + LayerNorm + tanh + fused qcode.
// ---------------------------------------------------------------------------
__global__ void qproj_fin(const double* __restrict__ partial,
                          const float* __restrict__ bq,
                          const float* __restrict__ gamma,
                          const float* __restrict__ beta,
                          const float* __restrict__ proj,
                          float* __restrict__ out_qv,
                          double* __restrict__ qv64,
                          unsigned* __restrict__ qcp,
                          unsigned* __restrict__ cnt) {
  const int q = blockIdx.x, e = threadIdx.x;
  __shared__ double red[256];
  __shared__ double qd[256];
  __shared__ double s_mu, s_rs;

  if (e == 0) cnt[q] = 0u;

  double acc = 0.0;
#pragma unroll
  for (int kc = 0; kc < KC; ++kc)
    acc += partial[((size_t)kc * Bq + q) * Ed + e];
  acc += (double)bq[e];

  red[e] = acc;
  __syncthreads();
  for (int s = 128; s > 0; s >>= 1) {
    if (e < s) red[e] += red[e + s];
    __syncthreads();
  }
  if (e == 0) s_mu = red[0] / 256.0;
  __syncthreads();
  double d = acc - s_mu;
  red[e] = d * d;
  __syncthreads();
  for (int s = 128; s > 0; s >>= 1) {
    if (e < s) red[e] += red[e + s];
    __syncthreads();
  }
  if (e == 0) s_rs = 1.0 / sqrt(red[0] / 256.0 + 1e-5);
  __syncthreads();

  double y = (acc - s_mu) * s_rs * (double)gamma[e] + (double)beta[e];
  double t = tanh(y);
  out_qv[(size_t)q * Ed + e] = (float)t;
  qv64[(size_t)q * Ed + e] = t;
  qd[e] = t;
  __syncthreads();

  double dot = 0.0;
  if (e < 32) {
    const int tt = e >> 3, b = e & 7;
    const float* pp = proj + (size_t)tt * Ed * NBITS + b;
#pragma unroll 4
    for (int ee = 0; ee < Ed; ++ee)
      dot = fma(qd[ee], (double)pp[(size_t)ee * NBITS], dot);
  }
  unsigned long long mask = __ballot(e < 32 && dot > 0.0);
  if (e == 0) qcp[q] = (unsigned)mask;
}

// ---------------------------------------------------------------------------
// Kernel I (v8): f32 LDS tile, wave-uniform table -> proj in SGPRs.
// grid 3125 x 256. Block = 64 items; wave w computes table w (8 bits/thread).
// Tile [64][65] f32 (odd stride -> (i+e)%32 banks, 2-way free both ways),
// 16.6 KB -> 8 blocks/CU (~full occupancy). Staging: dword-coalesced reads +
// fused bf16 emit (one full 128B line per store instr). Compute: per e
// 1 conflict-free ds_read_b32 + 8 FMA (proj via s_load, scalar pipe).
// f32 accumulate, thr 2e-4, per-bit f64 recompute from original f32 item
// (R4-R6 proven exact). Pack via LDS atomicOr.
// ---------------------------------------------------------------------------
__global__ void __launch_bounds__(256) icode_kernel(
    const float* __restrict__ item,
    const float* __restrict__ proj,
    unsigned* __restrict__ icodes,
    unsigned short* __restrict__ ibf) {
  __shared__ float ts[IPB * 65];       // 16640 B
  __shared__ unsigned icode_s[IPB];
  const int tid = threadIdx.x;
  const int base = blockIdx.x * IPB;
  const int il = tid & 63;
  const int t = __builtin_amdgcn_readfirstlane(tid >> 6);
  const float* pt = proj + (size_t)t * (Ed * NBITS);   // [e][8]

  if (tid < IPB) icode_s[tid] = 0u;

  float acc[8];
#pragma unroll
  for (int b = 0; b < 8; ++b) acc[b] = 0.0f;

  for (int c = 0; c < 4; ++c) {        // 4 chunks of 64 e
    __syncthreads();
    // stage 64 rows x 64 e: fi = rep*256+tid -> row=fi>>6, e=fi&63
#pragma unroll
    for (int rep = 0; rep < 16; ++rep) {
      const int fi = rep * 256 + tid;
      const int row = fi >> 6, e = fi & 63;
      const float v = item[(size_t)(base + row) * Ed + c * 64 + e];
      ts[row * 65 + e] = v;
      ibf[(size_t)(base + row) * Ed + c * 64 + e] = f2bf(v);
    }
    __syncthreads();

#pragma unroll 8
    for (int e = 0; e < 64; ++e) {
      const float av = ts[il * 65 + e];
      const float4 pa = *reinterpret_cast<const float4*>(&pt[(size_t)(c * 64 + e) * 8]);
      const float4 pb = *reinterpret_cast<const float4*>(&pt[(size_t)(c * 64 + e) * 8 + 4]);
      acc[0] = fmaf(av, pa.x, acc[0]);
      acc[1] = fmaf(av, pa.y, acc[1]);
      acc[2] = fmaf(av, pa.z, acc[2]);
      acc[3] = fmaf(av, pa.w, acc[3]);
      acc[4] = fmaf(av, pb.x, acc[4]);
      acc[5] = fmaf(av, pb.y, acc[5]);
      acc[6] = fmaf(av, pb.z, acc[6]);
      acc[7] = fmaf(av, pb.w, acc[7]);
    }
  }

  unsigned byte = 0, bl = 0;
#pragma unroll
  for (int b = 0; b < 8; ++b) {
    byte |= (acc[b] > 0.0f ? 1u : 0u) << b;
    bl |= (fabsf(acc[b]) < 2e-4f ? 1u : 0u) << b;
  }

  if (bl) {   // rare exact f64 path (~0.016% of bits)
    const int gi = base + il;
    const float* er = item + (size_t)gi * Ed;
    while (bl) {
      const int b = __builtin_ctz(bl);
      bl &= bl - 1;
      const float* pp = pt + b;
      double a = 0.0;
      for (int e2 = 0; e2 < Ed; ++e2)
        a = fma((double)er[e2], (double)pp[(size_t)e2 * NBITS], a);
      if (a > 0.0) byte |= 1u << b; else byte &= ~(1u << b);
    }
  }

  atomicOr(&icode_s[il], byte << (8 * t));
  __syncthreads();
  if (tid < IPB) icodes[base + tid] = icode_s[tid];
}

// ---------------------------------------------------------------------------
// Kernel F: fused match + candidate scoring. grid (256 q, 8 slices) x 256.
// ---------------------------------------------------------------------------
__global__ void __launch_bounds__(256) score_kernel(
    const float* __restrict__ qvf,
    const unsigned short* __restrict__ ibf,
    const unsigned* __restrict__ icodes,
    const unsigned* __restrict__ qcp,
    unsigned* __restrict__ cnt,
    unsigned long long* __restrict__ list) {
  __shared__ unsigned long long buf[CAPB];   // 24 KB
  __shared__ int lcnt;
  __shared__ unsigned sbase;

  const int tid = threadIdx.x;
  const int q = blockIdx.x;
  const int sl = blockIdx.y;
  const int l = tid & 63, wid = tid >> 6;

  if (tid == 0) lcnt = 0;
  const unsigned qc = qcp[q];
  const float4 qv4 = *reinterpret_cast<const float4*>(&qvf[(size_t)q * Ed + l * 4]);
  __syncthreads();

  const int i0 = sl * ISLICE, i1 = i0 + ISLICE;
  for (int bse = i0 + wid * 64; bse < i1; bse += 256) {
    const int i = bse + l;
    bool m = (i < i1) && anybyte_eq(qc, icodes[i]);
    unsigned long long mask = __ballot(m);
    while (mask) {
      const int b = __builtin_ctzll(mask);
      mask &= mask - 1;
      const int ii = bse + b;
      ushort4 hv = *reinterpret_cast<const ushort4*>(&ibf[(size_t)ii * Ed + l * 4]);
      float p = fmaf(bf2f(hv.x), qv4.x,
                fmaf(bf2f(hv.y), qv4.y,
                fmaf(bf2f(hv.z), qv4.z, bf2f(hv.w) * qv4.w)));
#pragma unroll
      for (int off = 1; off < 64; off <<= 1) p += __shfl_xor(p, off);
      if (l == 0) {
        int pos = atomicAdd(&lcnt, 1);
        if (pos < CAPB)
          buf[pos] = ((unsigned long long)fkey(p) << 32) |
                     (unsigned)(~(unsigned)ii);
      }
    }
  }
  __syncthreads();

  const int nl = lcnt;
  if (nl > CAPB) {           // overflow: force brute-force fallback for q
    if (tid == 0) atomicAdd(&cnt[q], (unsigned)(CAPL + 1));
    return;
  }
  if (tid == 0) sbase = atomicAdd(&cnt[q], (unsigned)nl);
  __syncthreads();
  const unsigned bp = sbase;
  for (int j = tid; j < nl; j += 256) {
    unsigned p = bp + (unsigned)j;
    if (p < CAPL) list[(size_t)q * CAPL + p] = buf[j];
  }
}

// ---------------------------------------------------------------------------
// Kernel FB: brute-force fallback for queries with cnt<Mm or overflow.
// ---------------------------------------------------------------------------
__global__ void fallback_kernel(const double* __restrict__ qv64,
                                const float* __restrict__ item,
                                const unsigned* __restrict__ qcp,
                                const unsigned* __restrict__ icodes,
                                unsigned* __restrict__ cnt,
                                unsigned long long* __restrict__ list) {
  const int q = blockIdx.x, tid = threadIdx.x;
  unsigned c = cnt[q];
  if (c >= (unsigned)Mm && c <= (unsigned)CAPL) return;

  __shared__ unsigned hist[NBINS];
  __shared__ float qf[256];
  __shared__ unsigned partial_[256];
  __shared__ int sbeta, scnt;

  qf[tid] = (float)qv64[(size_t)q * Ed + tid];
  for (int j = tid; j < NBINS; j += 256) hist[j] = 0u;
  if (tid == 0) scnt = 0;
  __syncthreads();

  const unsigned qc = qcp[q];
  for (int i = tid; i < Ni; i += 256) {
    float s = 0.0f;
    const float* er = item + (size_t)i * Ed;
    for (int e = 0; e < Ed; ++e) s = fmaf(qf[e], er[e], s);
    if (!anybyte_eq(qc, icodes[i])) s -= 1.0e6f;
    atomicAdd(&hist[fkey(s) >> 19], 1u);
  }
  __syncthreads();

  int beta = find_beta(hist, partial_, &sbeta, tid, Mm);
  __syncthreads();

  for (int i = tid; i < Ni; i += 256) {
    float s = 0.0f;
    const float* er = item + (size_t)i * Ed;
    for (int e = 0; e < Ed; ++e) s = fmaf(qf[e], er[e], s);
    if (!anybyte_eq(qc, icodes[i])) s -= 1.0e6f;
    unsigned k = fkey(s);
    if ((int)(k >> 19) >= beta) {
      int pos = atomicAdd(&scnt, 1);
      if (pos < CAPL)
        list[(size_t)q * CAPL + pos] =
            ((unsigned long long)k << 32) | (unsigned)(~(unsigned)i);
    }
  }
  __syncthreads();
  if (tid == 0) cnt[q] = (unsigned)(scnt < CAPL ? scnt : CAPL);
}

// ---------------------------------------------------------------------------
// Kernel D: top-128 select from compact list (hist threshold + bitonic).
// ---------------------------------------------------------------------------
__global__ void select_kernel(const unsigned long long* __restrict__ list,
                              const unsigned* __restrict__ cnt,
                              unsigned* __restrict__ cand) {
  __shared__ unsigned long long buf[CAP2];   // 32 KB (aliased with hist)
  __shared__ unsigned partial_[256];
  __shared__ int sbeta, scnt;
  unsigned* hist = reinterpret_cast<unsigned*>(buf);

  const int q = blockIdx.x, tid = threadIdx.x;
  const unsigned long long* src = list + (size_t)q * CAPL;
  const int count = min((int)cnt[q], CAPL);

  for (int j = tid; j < NBINS; j += 256) hist[j] = 0u;
  if (tid == 0) scnt = 0;
  __syncthreads();

  for (int i = tid; i < count; i += 256)
    atomicAdd(&hist[(unsigned)(src[i] >> 32) >> 19], 1u);
  __syncthreads();

  int beta = find_beta(hist, partial_, &sbeta, tid, Mm);
  __syncthreads();   // hist dead; buf reuse begins

  for (int i = tid; i < count; i += 256) {
    unsigned long long v = src[i];
    if ((int)((unsigned)(v >> 32) >> 19) >= beta) {
      int pos = atomicAdd(&scnt, 1);
      if (pos < CAP2) buf[pos] = v;
    }
  }
  __syncthreads();

  int sc = min(scnt, CAP2);
  int n = Mm;
  while (n < sc) n <<= 1;
  for (int j = tid; j < n; j += 256)
    if (j >= sc) buf[j] = 0ull;
  __syncthreads();

  for (int k2 = 2; k2 <= n; k2 <<= 1) {
    for (int j = k2 >> 1; j > 0; j >>= 1) {
      for (int i = tid; i < n; i += 256) {
        int p = i ^ j;
        if (p > i) {
          bool up = ((i & k2) == 0);
          unsigned long long a = buf[i], b = buf[p];
          if ((a < b) == up) { buf[i] = b; buf[p] = a; }
        }
      }
      __syncthreads();
    }
  }

  if (tid < Mm)
    cand[q * Mm + tid] = ~(unsigned)(buf[tid] & 0xFFFFFFFFull);
}

// ---------------------------------------------------------------------------
// Kernel E: f64 re-rank of 128 candidates (wave-cooperative dots);
// sort (score desc, id asc); emit 100 ids (as f32) + gathered embeddings.
// ---------------------------------------------------------------------------
__global__ void rerank_kernel(const double* __restrict__ qv64,
                              const float* __restrict__ item,
                              const unsigned* __restrict__ qcp,
                              const unsigned* __restrict__ icodes,
                              const unsigned* __restrict__ cand,
                              float* __restrict__ out_ids,
                              float* __restrict__ out_emb) {
  const int q = blockIdx.x, tid = threadIdx.x;
  const int l = tid & 63, w = tid >> 6;
  __shared__ double qr[Ed];
  __shared__ double sc[Mm];
  __shared__ int sid[Mm];

  qr[tid] = qv64[(size_t)q * Ed + tid];
  if (tid < Mm) {
    int id = (int)cand[q * Mm + tid];
    if (id < 0 || id >= Ni) id = 0;
    sid[tid] = id;
  }
  __syncthreads();

  const unsigned qc = qcp[q];
  for (int cc = 0; cc < Mm / 4; ++cc) {
    const int ci = w * (Mm / 4) + cc;
    const int id = sid[ci];
    float4 ev = *reinterpret_cast<const float4*>(&item[(size_t)id * Ed + l * 4]);
    double p = fma((double)ev.x, qr[l * 4 + 0],
               fma((double)ev.y, qr[l * 4 + 1],
               fma((double)ev.z, qr[l * 4 + 2],
                   (double)ev.w * qr[l * 4 + 3])));
#pragma unroll
    for (int off = 32; off > 0; off >>= 1) p += __shfl_down(p, off);
    if (l == 0) {
      double s = p;
      if (!anybyte_eq(qc, icodes[id])) s -= 1.0e6;
      sc[ci] = s;
    }
  }
  __syncthreads();

  for (int k2 = 2; k2 <= Mm; k2 <<= 1) {
    for (int j = k2 >> 1; j > 0; j >>= 1) {
      for (int i = tid; i < Mm; i += 256) {
        int p = i ^ j;
        if (p > i) {
          bool up = ((i & k2) == 0);
          double sa = sc[i], sb = sc[p];
          int ia = sid[i], ib = sid[p];
          bool aAfterB = (sa < sb) || (sa == sb && ia > ib);
          if (aAfterB == up) {
            sc[i] = sb; sc[p] = sa;
            sid[i] = ib; sid[p] = ia;
          }
        }
      }
      __syncthreads();
    }
  }

  if (tid < Kk) out_ids[q * Kk + tid] = (float)sid[tid];
  for (int f = tid; f < Kk * 64; f += 256) {
    int r = f >> 6, c4 = f & 63;
    *reinterpret_cast<float4*>(&out_emb[((size_t)q * Kk + r) * Ed + c4 * 4]) =
        *reinterpret_cast<const float4*>(&item[(size_t)sid[r] * Ed + c4 * 4]);
  }
}

// ---------------------------------------------------------------------------
extern "C" void kernel_launch(void* const* d_in, const int* in_sizes, int n_in,
                              void* d_out, int out_size, void* d_ws, size_t ws_size,
                              hipStream_t stream) {
  const float* hidden = (const float*)d_in[0];
  const float* Wq     = (const float*)d_in[1];
  const float* bq     = (const float*)d_in[2];
  const float* gamma  = (const float*)d_in[3];
  const float* beta   = (const float*)d_in[4];
  const float* proj   = (const float*)d_in[5];
  const float* item   = (const float*)d_in[6];

  float* out = (float*)d_out;
  char* ws = (char*)d_ws;
  double*             qv64 = (double*)(ws + OFF_QV64);
  unsigned*           qcp  = (unsigned*)(ws + OFF_QC);
  unsigned*           ic   = (unsigned*)(ws + OFF_IC);
  unsigned*           cnt  = (unsigned*)(ws + OFF_CNT);
  unsigned*           cand = (unsigned*)(ws + OFF_CAND);
  unsigned short*     ibf  = (unsigned short*)(ws + OFF_IBF);
  unsigned long long* list = (unsigned long long*)(ws + OFF_LIST);
  double*             part = (double*)(ws + OFF_PART);

  qproj_gemm<<<dim3(QT, KC), dim3(256), 0, stream>>>(hidden, Wq, part);
  icode_kernel<<<dim3(Ni / IPB), dim3(256), 0, stream>>>(item, proj, ic, ibf);
  qproj_fin<<<dim3(Bq), dim3(256), 0, stream>>>(part, bq, gamma, beta, proj,
                                                out, qv64, qcp, cnt);
  score_kernel<<<dim3(Bq, NSLICE), dim3(256), 0, stream>>>(out, ibf, ic, qcp, cnt, list);
  fallback_kernel<<<dim3(Bq), dim3(256), 0, stream>>>(qv64, item, qcp, ic, cnt, list);
  select_kernel<<<dim3(Bq), dim3(256), 0, stream>>>(list, cnt, cand);
  rerank_kernel<<<dim3(Bq), dim3(256), 0, stream>>>(
      qv64, item, qcp, ic, cand,
      out + (size_t)Bq * Ed, out + (size_t)Bq * Ed + (size_t)Bq * Kk);
}

// Round 11
// 287.542 us; speedup vs baseline: 3.1528x; 1.5424x over previous
//
#include <hip/hip_runtime.h>
#include <math.h>

// Problem constants
#define Bq   256
#define Hd   2048
#define Ed   256
#define Ni   200000
#define Tt   4
#define NBITS 8
#define Kk   100
#define Mm   128            // rerank margin: top-128 by approx key superset of true top-100
#define CAPL 16384          // per-query compact candidate list capacity
#define CAPB 2048           // per-block LDS match buffer (slice expects ~194)
#define CAP2 4096           // select LDS collect capacity
#define NBINS 8192
#define NSLICE 16
#define ISLICE (Ni / NSLICE)   // 12500
#define IPB 64               // icode items per block (200000/64 = 3125 exact)
#define QPB 8                // qproj queries per block
#define QT  (Bq / QPB)       // 32 q-tiles
#define KC  16               // k-chunks
#define KCH (Hd / KC)        // 128

// ws layout (bytes) — total ~145.8 MB
#define OFF_QV64  0ull            // 256*256*8   = 524288
#define OFF_QC    524288ull       // 256*4       = 1024
#define OFF_IC    525312ull       // 200000*4    = 800000
#define OFF_CNT   1325312ull      // 256*4       = 1024
#define OFF_CAND  1326336ull      // 256*128*4   = 131072
#define OFF_IBF   1457408ull      // (retired)
#define OFF_LIST  103857408ull    // 256*16384*8  = 33554432
#define OFF_PART  137411840ull    // 16*256*256*8 = 8388608

__device__ __forceinline__ unsigned short f2bf(float x) {
  unsigned u = __float_as_uint(x);
  return (unsigned short)((u + 0x7FFFu + ((u >> 16) & 1u)) >> 16);
}
__device__ __forceinline__ bool anybyte_eq(unsigned a, unsigned b) {
  unsigned x = a ^ b;
  return ((x - 0x01010101u) & ~x & 0x80808080u) != 0u;
}
__device__ __forceinline__ unsigned fkey(float s) {
  unsigned u = __float_as_uint(s);
  return (u & 0x80000000u) ? ~u : (u | 0x80000000u);
}

// histogram beta-find helper (shared across select/fallback)
__device__ __forceinline__ int find_beta(unsigned* hist, unsigned* partial_,
                                         int* sbeta, int tid, int target) {
  unsigned s = 0;
#pragma unroll 8
  for (int j = 0; j < 32; ++j) s += hist[tid * 32 + j];
  partial_[tid] = s;
  __syncthreads();
  if (tid == 0) {
    unsigned cum = 0;
    int c;
    for (c = 255; c > 0; --c) {
      if (cum + partial_[c] >= (unsigned)target) break;
      cum += partial_[c];
    }
    int b;
    for (b = c * 32 + 31; b > c * 32; --b) {
      if (cum + hist[b] >= (unsigned)target) break;
      cum += hist[b];
    }
    *sbeta = b;
  }
  __syncthreads();
  return *sbeta;
}

// ---------------------------------------------------------------------------
// Kernel A1: split-K f64 projection GEMM. grid (32 qtiles, 16 kchunks) x 256.
// ---------------------------------------------------------------------------
__global__ void __launch_bounds__(256) qproj_gemm(
    const float* __restrict__ hidden,
    const float* __restrict__ Wq,
    double* __restrict__ partial) {
  __shared__ float hs_t[KCH][QPB];   // [h][qq], 4 KB
  const int e = threadIdx.x;
  const int qbase = blockIdx.x * QPB;
  const int kc = blockIdx.y;

  for (int j = e; j < QPB * KCH; j += 256) {
    int qq = j >> 7, h = j & (KCH - 1);
    hs_t[h][qq] = hidden[(size_t)(qbase + qq) * Hd + kc * KCH + h];
  }
  __syncthreads();

  double acc[QPB];
#pragma unroll
  for (int qq = 0; qq < QPB; ++qq) acc[qq] = 0.0;

  for (int h = 0; h < KCH; ++h) {
    double w = (double)Wq[(size_t)(kc * KCH + h) * Ed + e];
    float4 ha = *reinterpret_cast<const float4*>(&hs_t[h][0]);
    float4 hb = *reinterpret_cast<const float4*>(&hs_t[h][4]);
    acc[0] = fma((double)ha.x, w, acc[0]);
    acc[1] = fma((double)ha.y, w, acc[1]);
    acc[2] = fma((double)ha.z, w, acc[2]);
    acc[3] = fma((double)ha.w, w, acc[3]);
    acc[4] = fma((double)hb.x, w, acc[4]);
    acc[5] = fma((double)hb.y, w, acc[5]);
    acc[6] = fma((double)hb.z, w, acc[6]);
    acc[7] = fma((double)hb.w, w, acc[7]);
  }

#pragma unroll
  for (int qq = 0; qq < QPB; ++qq)
    partial[((size_t)kc * Bq + qbase + qq) * Ed + e] = acc[qq];
}

// ---------------------------------------------------------------------------
// Kernel A2: finalize — sum 16 partials + LayerNorm + tanh + fused qcode.
// ---------------------------------------------------------------------------
__global__ void qproj_fin(const double* __restrict__ partial,
                          const float* __restrict__ bq,
                          const float* __restrict__ gamma,
                          const float* __restrict__ beta,
                          const float* __restrict__ proj,
                          float* __restrict__ out_qv,
                          double* __restrict__ qv64,
                          unsigned* __restrict__ qcp,
                          unsigned* __restrict__ cnt) {
  const int q = blockIdx.x, e = threadIdx.x;
  __shared__ double red[256];
  __shared__ double qd[256];
  __shared__ double s_mu, s_rs;

  if (e == 0) cnt[q] = 0u;

  double acc = 0.0;
#pragma unroll
  for (int kc = 0; kc < KC; ++kc)
    acc += partial[((size_t)kc * Bq + q) * Ed + e];
  acc += (double)bq[e];

  red[e] = acc;
  __syncthreads();
  for (int s = 128; s > 0; s >>= 1) {
    if (e < s) red[e] += red[e + s];
    __syncthreads();
  }
  if (e == 0) s_mu = red[0] / 256.0;
  __syncthreads();
  double d = acc - s_mu;
  red[e] = d * d;
  __syncthreads();
  for (int s = 128; s > 0; s >>= 1) {
    if (e < s) red[e] += red[e + s];
    __syncthreads();
  }
  if (e == 0) s_rs = 1.0 / sqrt(red[0] / 256.0 + 1e-5);
  __syncthreads();

  double y = (acc - s_mu) * s_rs * (double)gamma[e] + (double)beta[e];
  double t = tanh(y);
  out_qv[(size_t)q * Ed + e] = (float)t;
  qv64[(size_t)q * Ed + e] = t;
  qd[e] = t;
  __syncthreads();

  double dot = 0.0;
  if (e < 32) {
    const int tt = e >> 3, b = e & 7;
    const float* pp = proj + (size_t)tt * Ed * NBITS + b;
#pragma unroll 4
    for (int ee = 0; ee < Ed; ++ee)
      dot = fma(qd[ee], (double)pp[(size_t)ee * NBITS], dot);
  }
  unsigned long long mask = __ballot(e < 32 && dot > 0.0);
  if (e == 0) qcp[q] = (unsigned)mask;
}

// ---------------------------------------------------------------------------
// Kernel I (v9 = R10 v8 minus ibf): f32 LDS tile, wave-uniform table ->
// proj in SGPRs. grid 3125 x 256. Tile [64][65] f32, 16.6 KB -> 8 blocks/CU.
// f32 accumulate, thr 2e-4, per-bit f64 recompute (R4-R6 proven exact).
// No bf16 emit — ibf retired (score now reads f32 item directly).
// ---------------------------------------------------------------------------
__global__ void __launch_bounds__(256) icode_kernel(
    const float* __restrict__ item,
    const float* __restrict__ proj,
    unsigned* __restrict__ icodes) {
  __shared__ float ts[IPB * 65];       // 16640 B
  __shared__ unsigned icode_s[IPB];
  const int tid = threadIdx.x;
  const int base = blockIdx.x * IPB;
  const int il = tid & 63;
  const int t = __builtin_amdgcn_readfirstlane(tid >> 6);
  const float* pt = proj + (size_t)t * (Ed * NBITS);   // [e][8]

  if (tid < IPB) icode_s[tid] = 0u;

  float acc[8];
#pragma unroll
  for (int b = 0; b < 8; ++b) acc[b] = 0.0f;

  for (int c = 0; c < 4; ++c) {        // 4 chunks of 64 e
    __syncthreads();
#pragma unroll
    for (int rep = 0; rep < 16; ++rep) {
      const int fi = rep * 256 + tid;
      const int row = fi >> 6, e = fi & 63;
      ts[row * 65 + e] = item[(size_t)(base + row) * Ed + c * 64 + e];
    }
    __syncthreads();

#pragma unroll 8
    for (int e = 0; e < 64; ++e) {
      const float av = ts[il * 65 + e];
      const float4 pa = *reinterpret_cast<const float4*>(&pt[(size_t)(c * 64 + e) * 8]);
      const float4 pb = *reinterpret_cast<const float4*>(&pt[(size_t)(c * 64 + e) * 8 + 4]);
      acc[0] = fmaf(av, pa.x, acc[0]);
      acc[1] = fmaf(av, pa.y, acc[1]);
      acc[2] = fmaf(av, pa.z, acc[2]);
      acc[3] = fmaf(av, pa.w, acc[3]);
      acc[4] = fmaf(av, pb.x, acc[4]);
      acc[5] = fmaf(av, pb.y, acc[5]);
      acc[6] = fmaf(av, pb.z, acc[6]);
      acc[7] = fmaf(av, pb.w, acc[7]);
    }
  }

  unsigned byte = 0, bl = 0;
#pragma unroll
  for (int b = 0; b < 8; ++b) {
    byte |= (acc[b] > 0.0f ? 1u : 0u) << b;
    bl |= (fabsf(acc[b]) < 2e-4f ? 1u : 0u) << b;
  }

  if (bl) {   // rare exact f64 path (~0.016% of bits)
    const int gi = base + il;
    const float* er = item + (size_t)gi * Ed;
    while (bl) {
      const int b = __builtin_ctz(bl);
      bl &= bl - 1;
      const float* pp = pt + b;
      double a = 0.0;
      for (int e2 = 0; e2 < Ed; ++e2)
        a = fma((double)er[e2], (double)pp[(size_t)e2 * NBITS], a);
      if (a > 0.0) byte |= 1u << b; else byte &= ~(1u << b);
    }
  }

  atomicOr(&icode_s[il], byte << (8 * t));
  __syncthreads();
  if (tid < IPB) icodes[base + tid] = icode_s[tid];
}

// ---------------------------------------------------------------------------
// Kernel F (v2): scan/process-decoupled match + scoring.
// grid (256 q, 16 slices) x 256. Scan: waves ballot matches, append ids to
// LDS queue. Process: 16 x 16-lane groups, each dots one candidate
// (f32 item row, 4 coalesced float4/lane, 4-step shfl reduce), overwrites
// its queue slot with (key,~id) in place. Flush: ONE global atomic + coalesced.
// ---------------------------------------------------------------------------
__global__ void __launch_bounds__(256) score_kernel(
    const float* __restrict__ qvf,
    const float* __restrict__ item,
    const unsigned* __restrict__ icodes,
    const unsigned* __restrict__ qcp,
    unsigned* __restrict__ cnt,
    unsigned long long* __restrict__ list) {
  __shared__ unsigned long long buf[CAPB];   // 16 KB: ids, then (key|~id)
  __shared__ int lcnt;
  __shared__ unsigned sbase;

  const int tid = threadIdx.x;
  const int q = blockIdx.x, sl = blockIdx.y;
  const int l = tid & 63, wid = tid >> 6;
  const int k = tid & 15;            // lane within 16-group
  const int gg = tid >> 4;           // group id 0..15

  if (tid == 0) lcnt = 0;
  const unsigned qc = qcp[q];

  // per-thread qv fragment: elements (c*16+k)*4 .. +4, c = 0..3
  float4 qv[4];
#pragma unroll
  for (int c = 0; c < 4; ++c)
    qv[c] = *reinterpret_cast<const float4*>(&qvf[(size_t)q * Ed + (c * 16 + k) * 4]);
  __syncthreads();

  // ---- scan phase ----
  const int i0 = sl * ISLICE, i1 = i0 + ISLICE;
  for (int bse = i0 + wid * 64; bse < i1; bse += 256) {
    const int i = bse + l;
    bool m = (i < i1) && anybyte_eq(qc, icodes[i]);
    unsigned long long mask = __ballot(m);
    if (l == 0 && mask) {
      int n = __popcll(mask);
      int pos = atomicAdd(&lcnt, n);
      while (mask) {
        const int b = __builtin_ctzll(mask);
        mask &= mask - 1;
        if (pos < CAPB) buf[pos] = (unsigned long long)(unsigned)(bse + b);
        ++pos;
      }
    }
  }
  __syncthreads();

  if (lcnt > CAPB) {   // overflow: force brute-force fallback for q
    if (tid == 0) atomicAdd(&cnt[q], (unsigned)(CAPL + 1));
    return;
  }
  const int nl = lcnt;

  // ---- process phase: 16 concurrent group-dots ----
  for (int b = gg; b < nl; b += 16) {
    const int id = (int)(unsigned)buf[b];
    const float* row = item + (size_t)id * Ed;
    float p = 0.0f;
#pragma unroll
    for (int c = 0; c < 4; ++c) {
      const float4 ev = *reinterpret_cast<const float4*>(&row[(c * 16 + k) * 4]);
      p = fmaf(ev.x, qv[c].x, fmaf(ev.y, qv[c].y,
          fmaf(ev.z, qv[c].z, fmaf(ev.w, qv[c].w, p))));
    }
#pragma unroll
    for (int off = 1; off < 16; off <<= 1) p += __shfl_xor(p, off);
    if (k == 0)
      buf[b] = ((unsigned long long)fkey(p) << 32) | (unsigned)(~(unsigned)id);
  }
  __syncthreads();

  // ---- flush ----
  if (tid == 0) sbase = atomicAdd(&cnt[q], (unsigned)nl);
  __syncthreads();
  const unsigned bp = sbase;
  for (int j = tid; j < nl; j += 256) {
    unsigned p = bp + (unsigned)j;
    if (p < CAPL) list[(size_t)q * CAPL + p] = buf[j];
  }
}

// ---------------------------------------------------------------------------
// Kernel FB: brute-force fallback for queries with cnt<Mm or overflow.
// ---------------------------------------------------------------------------
__global__ void fallback_kernel(const double* __restrict__ qv64,
                                const float* __restrict__ item,
                                const unsigned* __restrict__ qcp,
                                const unsigned* __restrict__ icodes,
                                unsigned* __restrict__ cnt,
                                unsigned long long* __restrict__ list) {
  const int q = blockIdx.x, tid = threadIdx.x;
  unsigned c = cnt[q];
  if (c >= (unsigned)Mm && c <= (unsigned)CAPL) return;

  __shared__ unsigned hist[NBINS];
  __shared__ float qf[256];
  __shared__ unsigned partial_[256];
  __shared__ int sbeta, scnt;

  qf[tid] = (float)qv64[(size_t)q * Ed + tid];
  for (int j = tid; j < NBINS; j += 256) hist[j] = 0u;
  if (tid == 0) scnt = 0;
  __syncthreads();

  const unsigned qc = qcp[q];
  for (int i = tid; i < Ni; i += 256) {
    float s = 0.0f;
    const float* er = item + (size_t)i * Ed;
    for (int e = 0; e < Ed; ++e) s = fmaf(qf[e], er[e], s);
    if (!anybyte_eq(qc, icodes[i])) s -= 1.0e6f;
    atomicAdd(&hist[fkey(s) >> 19], 1u);
  }
  __syncthreads();

  int beta = find_beta(hist, partial_, &sbeta, tid, Mm);
  __syncthreads();

  for (int i = tid; i < Ni; i += 256) {
    float s = 0.0f;
    const float* er = item + (size_t)i * Ed;
    for (int e = 0; e < Ed; ++e) s = fmaf(qf[e], er[e], s);
    if (!anybyte_eq(qc, icodes[i])) s -= 1.0e6f;
    unsigned kk = fkey(s);
    if ((int)(kk >> 19) >= beta) {
      int pos = atomicAdd(&scnt, 1);
      if (pos < CAPL)
        list[(size_t)q * CAPL + pos] =
            ((unsigned long long)kk << 32) | (unsigned)(~(unsigned)i);
    }
  }
  __syncthreads();
  if (tid == 0) cnt[q] = (unsigned)(scnt < CAPL ? scnt : CAPL);
}

// ---------------------------------------------------------------------------
// Kernel D: top-128 select from compact list (hist threshold + bitonic).
// ---------------------------------------------------------------------------
__global__ void select_kernel(const unsigned long long* __restrict__ list,
                              const unsigned* __restrict__ cnt,
                              unsigned* __restrict__ cand) {
  __shared__ unsigned long long buf[CAP2];   // 32 KB (aliased with hist)
  __shared__ unsigned partial_[256];
  __shared__ int sbeta, scnt;
  unsigned* hist = reinterpret_cast<unsigned*>(buf);

  const int q = blockIdx.x, tid = threadIdx.x;
  const unsigned long long* src = list + (size_t)q * CAPL;
  const int count = min((int)cnt[q], CAPL);

  for (int j = tid; j < NBINS; j += 256) hist[j] = 0u;
  if (tid == 0) scnt = 0;
  __syncthreads();

  for (int i = tid; i < count; i += 256)
    atomicAdd(&hist[(unsigned)(src[i] >> 32) >> 19], 1u);
  __syncthreads();

  int beta = find_beta(hist, partial_, &sbeta, tid, Mm);
  __syncthreads();   // hist dead; buf reuse begins

  for (int i = tid; i < count; i += 256) {
    unsigned long long v = src[i];
    if ((int)((unsigned)(v >> 32) >> 19) >= beta) {
      int pos = atomicAdd(&scnt, 1);
      if (pos < CAP2) buf[pos] = v;
    }
  }
  __syncthreads();

  int sc = min(scnt, CAP2);
  int n = Mm;
  while (n < sc) n <<= 1;
  for (int j = tid; j < n; j += 256)
    if (j >= sc) buf[j] = 0ull;
  __syncthreads();

  for (int k2 = 2; k2 <= n; k2 <<= 1) {
    for (int j = k2 >> 1; j > 0; j >>= 1) {
      for (int i = tid; i < n; i += 256) {
        int p = i ^ j;
        if (p > i) {
          bool up = ((i & k2) == 0);
          unsigned long long a = buf[i], b = buf[p];
          if ((a < b) == up) { buf[i] = b; buf[p] = a; }
        }
      }
      __syncthreads();
    }
  }

  if (tid < Mm)
    cand[q * Mm + tid] = ~(unsigned)(buf[tid] & 0xFFFFFFFFull);
}

// ---------------------------------------------------------------------------
// Kernel E: f64 re-rank of 128 candidates (wave-cooperative dots);
// sort (score desc, id asc); emit 100 ids (as f32) + gathered embeddings.
// ---------------------------------------------------------------------------
__global__ void rerank_kernel(const double* __restrict__ qv64,
                              const float* __restrict__ item,
                              const unsigned* __restrict__ qcp,
                              const unsigned* __restrict__ icodes,
                              const unsigned* __restrict__ cand,
                              float* __restrict__ out_ids,
                              float* __restrict__ out_emb) {
  const int q = blockIdx.x, tid = threadIdx.x;
  const int l = tid & 63, w = tid >> 6;
  __shared__ double qr[Ed];
  __shared__ double sc[Mm];
  __shared__ int sid[Mm];

  qr[tid] = qv64[(size_t)q * Ed + tid];
  if (tid < Mm) {
    int id = (int)cand[q * Mm + tid];
    if (id < 0 || id >= Ni) id = 0;
    sid[tid] = id;
  }
  __syncthreads();

  const unsigned qc = qcp[q];
  for (int cc = 0; cc < Mm / 4; ++cc) {
    const int ci = w * (Mm / 4) + cc;
    const int id = sid[ci];
    float4 ev = *reinterpret_cast<const float4*>(&item[(size_t)id * Ed + l * 4]);
    double p = fma((double)ev.x, qr[l * 4 + 0],
               fma((double)ev.y, qr[l * 4 + 1],
               fma((double)ev.z, qr[l * 4 + 2],
                   (double)ev.w * qr[l * 4 + 3])));
#pragma unroll
    for (int off = 32; off > 0; off >>= 1) p += __shfl_down(p, off);
    if (l == 0) {
      double s = p;
      if (!anybyte_eq(qc, icodes[id])) s -= 1.0e6;
      sc[ci] = s;
    }
  }
  __syncthreads();

  for (int k2 = 2; k2 <= Mm; k2 <<= 1) {
    for (int j = k2 >> 1; j > 0; j >>= 1) {
      for (int i = tid; i < Mm; i += 256) {
        int p = i ^ j;
        if (p > i) {
          bool up = ((i & k2) == 0);
          double sa = sc[i], sb = sc[p];
          int ia = sid[i], ib = sid[p];
          bool aAfterB = (sa < sb) || (sa == sb && ia > ib);
          if (aAfterB == up) {
            sc[i] = sb; sc[p] = sa;
            sid[i] = ib; sid[p] = ia;
          }
        }
      }
      __syncthreads();
    }
  }

  if (tid < Kk) out_ids[q * Kk + tid] = (float)sid[tid];
  for (int f = tid; f < Kk * 64; f += 256) {
    int r = f >> 6, c4 = f & 63;
    *reinterpret_cast<float4*>(&out_emb[((size_t)q * Kk + r) * Ed + c4 * 4]) =
        *reinterpret_cast<const float4*>(&item[(size_t)sid[r] * Ed + c4 * 4]);
  }
}

// ---------------------------------------------------------------------------
extern "C" void kernel_launch(void* const* d_in, const int* in_sizes, int n_in,
                              void* d_out, int out_size, void* d_ws, size_t ws_size,
                              hipStream_t stream) {
  const float* hidden = (const float*)d_in[0];
  const float* Wq     = (const float*)d_in[1];
  const float* bq     = (const float*)d_in[2];
  const float* gamma  = (const float*)d_in[3];
  const float* beta   = (const float*)d_in[4];
  const float* proj   = (const float*)d_in[5];
  const float* item   = (const float*)d_in[6];

  float* out = (float*)d_out;
  char* ws = (char*)d_ws;
  double*             qv64 = (double*)(ws + OFF_QV64);
  unsigned*           qcp  = (unsigned*)(ws + OFF_QC);
  unsigned*           ic   = (unsigned*)(ws + OFF_IC);
  unsigned*           cnt  = (unsigned*)(ws + OFF_CNT);
  unsigned*           cand = (unsigned*)(ws + OFF_CAND);
  unsigned long long* list = (unsigned long long*)(ws + OFF_LIST);
  double*             part = (double*)(ws + OFF_PART);

  qproj_gemm<<<dim3(QT, KC), dim3(256), 0, stream>>>(hidden, Wq, part);
  icode_kernel<<<dim3(Ni / IPB), dim3(256), 0, stream>>>(item, proj, ic);
  qproj_fin<<<dim3(Bq), dim3(256), 0, stream>>>(part, bq, gamma, beta, proj,
                                                out, qv64, qcp, cnt);
  score_kernel<<<dim3(Bq, NSLICE), dim3(256), 0, stream>>>(out, item, ic, qcp, cnt, list);
  fallback_kernel<<<dim3(Bq), dim3(256), 0, stream>>>(qv64, item, qcp, ic, cnt, list);
  select_kernel<<<dim3(Bq), dim3(256), 0, stream>>>(list, cnt, cand);
  rerank_kernel<<<dim3(Bq), dim3(256), 0, stream>>>(
      qv64, item, qcp, ic, cand,
      out + (size_t)Bq * Ed, out + (size_t)Bq * Ed + (size_t)Bq * Kk);
}